// Round 2
// baseline (1265.513 us; speedup 1.0000x reference)
//
#include <hip/hip_runtime.h>

// LaplacianBuilder: N=1024 nodes, E=16384 undirected edges, D=16 block dim.
// Output L is (N*16)^2 f32 = 1 GiB, block-sparse (33792 nonzero 16x16 blocks):
//   L[r,c] = -dinv[r]*dinv[c]*(Mf^T Mt)  for triu edge (r,c); L[c,r] = transpose
//   L[n,n] = dinv[n]^2 * sum_{e: src[e]==n} M_e^T M_e
// Round 2: custom high-occupancy zero-fill (rocclr fill ran at ~10% occupancy),
// and CSR-based diagonal (removes 8.4M contended atomics -> 32K cheap ones).

#define NN 1024
#define EE 16384
#define LD (NN * 16)      // 16384
#define CSR_STRIDE 128    // max degree headroom (avg deg = 32)

// ---- ws layout: [0,1024) int counters | [1024, 1024+NN*CSR_STRIDE) int csr ----

__global__ __launch_bounds__(256) void zero_counters(int* __restrict__ cnt) {
    cnt[blockIdx.x * 256 + threadIdx.x] = 0;   // grid 4 x 256 = 1024
}

__global__ __launch_bounds__(256) void build_csr(const int* __restrict__ edge_index,
                                                 int* __restrict__ cnt,
                                                 int* __restrict__ csr) {
    const int e = blockIdx.x * 256 + threadIdx.x;   // 0 .. 2E-1 (grid = 128)
    const int n = edge_index[e];                    // src of directed edge e
    const int slot = atomicAdd(&cnt[n], 1);
    csr[n * CSR_STRIDE + slot] = e;
}

__global__ __launch_bounds__(256) void zero_fill(float4* __restrict__ out, long n4) {
    const float4 z = make_float4(0.f, 0.f, 0.f, 0.f);
    long i = (long)blockIdx.x * 256 + threadIdx.x;
    const long stride = (long)gridDim.x * 256;
    for (; i < n4; i += stride)
        out[i] = z;
}

__global__ __launch_bounds__(256) void lap_blocks(
    const float* __restrict__ maps,       // [2E][16][16]
    const float* __restrict__ degrees,    // [N]
    const int*   __restrict__ edge_index, // [2][2E]
    const int*   __restrict__ csr,
    float* __restrict__ out)              // [16384][16384]
{
    __shared__ float Mf[256];
    __shared__ float Mt[256];
    const int t = threadIdx.x;
    const int j = t >> 4;      // row within 16x16 block
    const int k = t & 15;      // col within 16x16 block
    const int b = blockIdx.x;

    if (b < EE) {
        // ---- off-diagonal blocks for triu edge b ----
        const int src = edge_index[b];
        const int dst = edge_index[2 * EE + b];
        Mf[t] = maps[(size_t)b * 256 + t];
        Mt[t] = maps[(size_t)(b + EE) * 256 + t];
        __syncthreads();
        const float s = rsqrtf(degrees[src] * 16.0f + 1.0f) *
                        rsqrtf(degrees[dst] * 16.0f + 1.0f);
        float tjk = 0.0f, tkj = 0.0f;
        #pragma unroll
        for (int i = 0; i < 16; ++i) {
            const float fj = Mf[i * 16 + j];
            const float fk = Mf[i * 16 + k];
            const float gj = Mt[i * 16 + j];
            const float gk = Mt[i * 16 + k];
            tjk += fj * gk;   // T[j,k]
            tkj += fk * gj;   // T[k,j]
        }
        out[(size_t)(src * 16 + j) * LD + (dst * 16 + k)] = -s * tjk;
        out[(size_t)(dst * 16 + j) * LD + (src * 16 + k)] = -s * tkj;
    } else {
        // ---- diagonal block for node n ----
        const int n = b - EE;
        const int deg = (int)degrees[n];
        float acc = 0.0f;
        for (int q = 0; q < deg; ++q) {
            const int e = csr[n * CSR_STRIDE + q];
            __syncthreads();
            Mf[t] = maps[(size_t)e * 256 + t];
            __syncthreads();
            #pragma unroll
            for (int i = 0; i < 16; ++i)
                acc += Mf[i * 16 + j] * Mf[i * 16 + k];
        }
        const float di = rsqrtf(degrees[n] * 16.0f + 1.0f);
        out[(size_t)(n * 16 + j) * LD + (n * 16 + k)] = acc * di * di;
    }
}

extern "C" void kernel_launch(void* const* d_in, const int* in_sizes, int n_in,
                              void* d_out, int out_size, void* d_ws, size_t ws_size,
                              hipStream_t stream) {
    // inputs: [0] adj_mat (unused), [1] degrees f32[N], [2] maps f32[2E*256],
    //         [3] edge_index int[2*2E]
    const float* degrees    = (const float*)d_in[1];
    const float* maps       = (const float*)d_in[2];
    const int*   edge_index = (const int*)d_in[3];
    float* out = (float*)d_out;

    int* cnt = (int*)d_ws;
    int* csr = cnt + 1024;

    zero_counters<<<NN / 256, 256, 0, stream>>>(cnt);
    build_csr<<<2 * EE / 256, 256, 0, stream>>>(edge_index, cnt, csr);
    zero_fill<<<4096, 256, 0, stream>>>((float4*)out, (long)out_size / 4);
    lap_blocks<<<EE + NN, 256, 0, stream>>>(maps, degrees, edge_index, csr, out);
}